// Round 5
// baseline (253.639 us; speedup 1.0000x reference)
//
#include <hip/hip_runtime.h>
#include <hip/hip_bf16.h>

// B=4, S=2048, E=512, H=8, D=64. out = attn(x@wq+bq, x@wk+bk, x@wv+bv),
// scores MULTIPLIED by 8 (reference divides by D^-0.5).
// Precision: split-bf16 (hi+lo) for Q/K projections and QK^T (rel err ~2^-17);
// plain bf16 for V and PV.
// Round 5: split-S attention (2 slices of 16 k-tiles) -> 4096 waves = 4/SIMD
// (round 4 lesson: occupancy is capped by TOTAL wave count, 2048 waves = 2/SIMD
// no matter the block shape). Partial (O,m,l) to ws + combine kernel.
// s_setprio(1) around MFMA clusters (T5, +4-7% on this structure per m191).

#define SE 2048
#define EB 512
#define BB 4
#define HH 8
#define DD 64
#define BHN (BB*HH)

typedef __attribute__((ext_vector_type(8))) short short8;
typedef __attribute__((ext_vector_type(4))) float f32x4;

#define MFMA16(a, b, c) __builtin_amdgcn_mfma_f32_16x16x32_bf16((a), (b), (c), 0, 0, 0)

#if __has_builtin(__builtin_amdgcn_exp2f)
#define EXP2(x) __builtin_amdgcn_exp2f(x)
#else
#define EXP2(x) exp2f(x)
#endif

__device__ __forceinline__ unsigned short f2bf(float f) {
    union { float f; unsigned u; } x; x.f = f;
    unsigned r = x.u + 0x7fffu + ((x.u >> 16) & 1u);
    return (unsigned short)(r >> 16);
}
__device__ __forceinline__ float bf2f(unsigned short b) {
    union { unsigned u; float f; } x; x.u = ((unsigned)b) << 16;
    return x.f;
}

// ---- prep 1: split x (fp32) into hi/lo bf16, vectorized ----
__global__ void xsplit_kernel(const float* __restrict__ x,
                              unsigned short* __restrict__ xh,
                              unsigned short* __restrict__ xl, int n4) {
    int i = blockIdx.x * blockDim.x + threadIdx.x;
    if (i >= n4) return;
    float4 v = reinterpret_cast<const float4*>(x)[i];
    float f[4] = {v.x, v.y, v.z, v.w};
    ushort4 hv, lv;
    unsigned short hh[4], ll[4];
#pragma unroll
    for (int j = 0; j < 4; j++) {
        hh[j] = f2bf(f[j]);
        ll[j] = f2bf(f[j] - bf2f(hh[j]));
    }
    hv.x = hh[0]; hv.y = hh[1]; hv.z = hh[2]; hv.w = hh[3];
    lv.x = ll[0]; lv.y = ll[1]; lv.z = ll[2]; lv.w = ll[3];
    reinterpret_cast<ushort4*>(xh)[i] = hv;
    reinterpret_cast<ushort4*>(xl)[i] = lv;
}

// ---- prep 2: split + transpose weights into wt[hi/lo] layout [3*512 n][512 k] ----
__global__ void wsplit_kernel(const float* __restrict__ wq, const float* __restrict__ wk,
                              const float* __restrict__ wv,
                              unsigned short* __restrict__ wth,
                              unsigned short* __restrict__ wtl) {
    int tid = blockIdx.x * blockDim.x + threadIdx.x;
    if (tid >= 3 * 512 * 512) return;
    int n = tid & 511;
    int k = (tid >> 9) & 511;
    int m = tid >> 18;
    const float* w = (m == 0) ? wq : ((m == 1) ? wk : wv);
    float v = w[k * 512 + n];            // w is [k_in][n_out]
    unsigned short hb = f2bf(v);
    int o = ((m * 512 + n) << 9) + k;    // wt is [n][k]
    wth[o] = hb;
    wtl[o] = f2bf(v - bf2f(hb));
}

// stage 32 rows (4 KB) of a [128][64]-bf16 tile: linear LDS dest,
// inverse-swizzled global source (so ds_read with byte^((row&7)<<4) is clean).
__device__ __forceinline__ void stage4(const unsigned short* __restrict__ g,
                                       char* lbase, int wave, int srow, int scol,
                                       int kk) {
#pragma unroll
    for (int j = 0; j < 4; j++) {
        __builtin_amdgcn_global_load_lds(
            (const __attribute__((address_space(1))) void*)(g + (size_t)(srow + j * 8) * 512 + kk + scol),
            (__attribute__((address_space(3))) void*)(lbase + wave * 4096 + j * 1024),
            16, 0, 0);
    }
}

// ---- proj v3: tiled GEMM [8192,512]@[512,512] x3, LDS-staged, swizzled ----
template <int THREE>
__global__ __launch_bounds__(256) void proj_kernel(
    const unsigned short* __restrict__ xh, const unsigned short* __restrict__ xl,
    const unsigned short* __restrict__ wth, const unsigned short* __restrict__ wtl,
    const float* __restrict__ bq, const float* __restrict__ bk, const float* __restrict__ bv,
    unsigned short* __restrict__ qh, unsigned short* __restrict__ ql,
    unsigned short* __restrict__ kh, unsigned short* __restrict__ kl,
    unsigned short* __restrict__ vt) {
    constexpr int NTILE = THREE ? 4 : 2;
    __shared__ unsigned short lds[NTILE * 8192];   // tiles of [128][64] bf16
    char* LB = (char*)lds;
    constexpr int AHB = 0;
    constexpr int ALB = THREE ? 16384 : 0;
    constexpr int BHB = THREE ? 32768 : 16384;
    constexpr int BLB = THREE ? 49152 : 0;

    const int lane = threadIdx.x & 63;
    const int wave = threadIdx.x >> 6;
    const int lr = lane & 15, lk = lane >> 4;
    const int mat = THREE ? blockIdx.z : 2;        // 0=q 1=k 2=v
    const int m0 = blockIdx.x * 128;
    const int n0 = blockIdx.y * 128;
    const int wr = wave >> 1, wc = wave & 1;

    const unsigned short* Ah = xh + (size_t)m0 * 512;
    const unsigned short* Al = xl + (size_t)m0 * 512;
    const unsigned short* Bh = wth + (size_t)(mat * 512 + n0) * 512;
    const unsigned short* Bl = wtl + (size_t)(mat * 512 + n0) * 512;

    const int srow = wave * 32 + (lane >> 3);
    const int scol = 8 * ((lane & 7) ^ (lane >> 3));
    const int swzr = (lr & 7) << 4;

    f32x4 acc[4][4];
#pragma unroll
    for (int mi = 0; mi < 4; mi++)
#pragma unroll
        for (int ni = 0; ni < 4; ni++)
#pragma unroll
            for (int r = 0; r < 4; r++) acc[mi][ni][r] = 0.f;

    for (int t = 0; t < 8; t++) {
        const int kk = t * 64;
        stage4(Ah, LB + AHB, wave, srow, scol, kk);
        if (THREE) stage4(Al, LB + ALB, wave, srow, scol, kk);
        stage4(Bh, LB + BHB, wave, srow, scol, kk);
        if (THREE) stage4(Bl, LB + BLB, wave, srow, scol, kk);
        __syncthreads();

#pragma unroll
        for (int ks = 0; ks < 2; ks++) {
            short8 ah[4], al[4], bh8[4], bl8[4];
            const int cb = (ks * 64 + lk * 16) ^ swzr;
#pragma unroll
            for (int i = 0; i < 4; i++) {
                const int ao = (wr * 64 + i * 16 + lr) * 128 + cb;
                const int bo = (wc * 64 + i * 16 + lr) * 128 + cb;
                ah[i] = *reinterpret_cast<const short8*>(LB + AHB + ao);
                if (THREE) al[i] = *reinterpret_cast<const short8*>(LB + ALB + ao);
                bh8[i] = *reinterpret_cast<const short8*>(LB + BHB + bo);
                if (THREE) bl8[i] = *reinterpret_cast<const short8*>(LB + BLB + bo);
            }
#pragma unroll
            for (int mi = 0; mi < 4; mi++)
#pragma unroll
                for (int ni = 0; ni < 4; ni++) {
                    acc[mi][ni] = MFMA16(ah[mi], bh8[ni], acc[mi][ni]);
                    if (THREE) {
                        acc[mi][ni] = MFMA16(ah[mi], bl8[ni], acc[mi][ni]);
                        acc[mi][ni] = MFMA16(al[mi], bh8[ni], acc[mi][ni]);
                    }
                }
        }
        __syncthreads();
    }

    const float* bias = THREE ? ((mat == 0) ? bq : bk) : bv;
#pragma unroll
    for (int ni = 0; ni < 4; ni++) {
        const int col = n0 + wc * 64 + ni * 16 + lr;
        const float bsv = bias[col];
        const int h = col >> 6, d = col & 63;
#pragma unroll
        for (int mi = 0; mi < 4; mi++) {
#pragma unroll
            for (int r = 0; r < 4; r++) {
                const int row = m0 + wr * 64 + mi * 16 + lk * 4 + r;
                const int b_ = row >> 11, s = row & 2047;
                const int bh_ = b_ * HH + h;
                const float val = acc[mi][ni][r] + bsv;
                if (THREE) {
                    const unsigned short hb = f2bf(val);
                    const int o = (bh_ * SE + s) * DD + d;
                    if (mat == 0) { qh[o] = hb; ql[o] = f2bf(val - bf2f(hb)); }
                    else          { kh[o] = hb; kl[o] = f2bf(val - bf2f(hb)); }
                } else {
                    vt[(bh_ * DD + d) * SE + s] = f2bf(val);
                }
            }
        }
    }
}

// ---- attention v4: 1-wave blocks, swapped QK^T, split-S over blockIdx.z ----
// SPLIT=1: each block does 16 k-tiles, writes unnormalized partial O + (m,l).
// SPLIT=0: fallback single-slice (writes out directly).
template <int SPLIT>
__global__ __launch_bounds__(64) void attn_kernel(
    const unsigned short* __restrict__ qh, const unsigned short* __restrict__ ql,
    const unsigned short* __restrict__ kh, const unsigned short* __restrict__ kl,
    const unsigned short* __restrict__ vt, float* __restrict__ opart,
    float* __restrict__ mlbuf, float* __restrict__ out) {
    __shared__ unsigned short plds[2][16 * 64];  // per-qs P tile (wave-private)
    const int lane = threadIdx.x & 63;
    const int lr = lane & 15, lk = lane >> 4;
    const int bh = blockIdx.x;               // 0..31
    const int b_ = bh >> 3, h = bh & 7;
    const int q0 = blockIdx.y * 32;
    const int base = bh * SE * DD;
    const unsigned short* vbase = vt + bh * DD * SE;
    const float CL = 11.54156031f;           // 8 * log2(e)
    const int swz = (lr & 7) << 4;

    short8 qhf[2][2], qlf[2][2];
#pragma unroll
    for (int qs = 0; qs < 2; qs++) {
        const int qoff = base + (q0 + qs * 16 + lr) * DD + lk * 8;
        qhf[qs][0] = *reinterpret_cast<const short8*>(qh + qoff);
        qhf[qs][1] = *reinterpret_cast<const short8*>(qh + qoff + 32);
        qlf[qs][0] = *reinterpret_cast<const short8*>(ql + qoff);
        qlf[qs][1] = *reinterpret_cast<const short8*>(ql + qoff + 32);
    }

    float m[2] = {-3.0e4f, -3.0e4f}, l[2] = {0.f, 0.f};
    f32x4 o[2][4];
#pragma unroll
    for (int qs = 0; qs < 2; qs++)
#pragma unroll
        for (int dnt = 0; dnt < 4; dnt++)
#pragma unroll
            for (int r = 0; r < 4; r++) o[qs][dnt][r] = 0.f;

    const int kt0 = SPLIT ? blockIdx.z * 16 : 0;
    const int ktN = SPLIT ? kt0 + 16 : 32;
    for (int kt = kt0; kt < ktN; kt++) {
        const int k0 = kt * 64;
        f32x4 s[2][4];
#pragma unroll
        for (int qs = 0; qs < 2; qs++)
#pragma unroll
            for (int knt = 0; knt < 4; knt++)
#pragma unroll
                for (int r = 0; r < 4; r++) s[qs][knt][r] = 0.f;

        __builtin_amdgcn_s_setprio(1);
#pragma unroll
        for (int knt = 0; knt < 4; knt++) {
            const int koff = base + (k0 + knt * 16 + lr) * DD + lk * 8;
            short8 kh0 = *reinterpret_cast<const short8*>(kh + koff);
            short8 kh1 = *reinterpret_cast<const short8*>(kh + koff + 32);
            short8 kl0 = *reinterpret_cast<const short8*>(kl + koff);
            short8 kl1 = *reinterpret_cast<const short8*>(kl + koff + 32);
#pragma unroll
            for (int qs = 0; qs < 2; qs++) {
                s[qs][knt] = MFMA16(kh0, qhf[qs][0], s[qs][knt]);
                s[qs][knt] = MFMA16(kh1, qhf[qs][1], s[qs][knt]);
                s[qs][knt] = MFMA16(kl0, qhf[qs][0], s[qs][knt]);
                s[qs][knt] = MFMA16(kl1, qhf[qs][1], s[qs][knt]);
                s[qs][knt] = MFMA16(kh0, qlf[qs][0], s[qs][knt]);
                s[qs][knt] = MFMA16(kh1, qlf[qs][1], s[qs][knt]);
            }
        }
        __builtin_amdgcn_s_setprio(0);

        short8 vf[4][2];
#pragma unroll
        for (int dnt = 0; dnt < 4; dnt++) {
            const unsigned short* vp = vbase + (dnt * 16 + lr) * SE + k0 + lk * 8;
            vf[dnt][0] = *reinterpret_cast<const short8*>(vp);
            vf[dnt][1] = *reinterpret_cast<const short8*>(vp + 32);
        }

#pragma unroll
        for (int qs = 0; qs < 2; qs++) {
            float mt = s[qs][0][0];
#pragma unroll
            for (int knt = 0; knt < 4; knt++)
#pragma unroll
                for (int r = 0; r < 4; r++) mt = fmaxf(mt, s[qs][knt][r]);
            mt = fmaxf(mt, __shfl_xor(mt, 16));
            mt = fmaxf(mt, __shfl_xor(mt, 32));

            if (!__all(mt <= m[qs] + 0.69314718f)) {
                const float mn = fmaxf(m[qs], mt);
                const float fac = EXP2((m[qs] - mn) * CL);
                l[qs] *= fac;
#pragma unroll
                for (int dnt = 0; dnt < 4; dnt++)
#pragma unroll
                    for (int r = 0; r < 4; r++) o[qs][dnt][r] *= fac;
                m[qs] = mn;
            }
            const float nm = -m[qs] * CL;
            float p[4][4];
            float rs = 0.f;
#pragma unroll
            for (int knt = 0; knt < 4; knt++)
#pragma unroll
                for (int r = 0; r < 4; r++) {
                    p[knt][r] = EXP2(fmaf(s[qs][knt][r], CL, nm));
                    rs += p[knt][r];
                }
            rs += __shfl_xor(rs, 16);
            rs += __shfl_xor(rs, 32);
            l[qs] += rs;

            unsigned short* my = &plds[qs][0];
#pragma unroll
            for (int knt = 0; knt < 4; knt++) {
                unsigned w0 = (unsigned)f2bf(p[knt][0]) | ((unsigned)f2bf(p[knt][1]) << 16);
                unsigned w1 = (unsigned)f2bf(p[knt][2]) | ((unsigned)f2bf(p[knt][3]) << 16);
                const int cb = (knt * 32 + lk * 8) ^ swz;
                *reinterpret_cast<uint2*>(reinterpret_cast<char*>(my) + lr * 128 + cb) =
                    make_uint2(w0, w1);
            }
        }

        __builtin_amdgcn_s_setprio(1);
#pragma unroll
        for (int qs = 0; qs < 2; qs++) {
            const char* my = reinterpret_cast<const char*>(&plds[qs][0]);
            short8 pa0 = *reinterpret_cast<const short8*>(my + lr * 128 + ((lk * 16) ^ swz));
            short8 pa1 = *reinterpret_cast<const short8*>(my + lr * 128 + ((64 + lk * 16) ^ swz));
#pragma unroll
            for (int dnt = 0; dnt < 4; dnt++) {
                o[qs][dnt] = MFMA16(vf[dnt][0], pa0, o[qs][dnt]);
                o[qs][dnt] = MFMA16(vf[dnt][1], pa1, o[qs][dnt]);
            }
        }
        __builtin_amdgcn_s_setprio(0);
    }

    if (SPLIT) {
        // write unnormalized partial O + (m,l) for the combine pass
        const int g = bh * 64 + blockIdx.y;
        float* ob = opart + ((size_t)g * 2 + blockIdx.z) * 2048;
        float* mlb = mlbuf + ((size_t)g * 2 + blockIdx.z) * 64;
#pragma unroll
        for (int qs = 0; qs < 2; qs++) {
            float* op = ob + (qs * 16 + lr) * 64 + lk * 4;
#pragma unroll
            for (int dnt = 0; dnt < 4; dnt++) {
                float4 val;
                val.x = o[qs][dnt][0]; val.y = o[qs][dnt][1];
                val.z = o[qs][dnt][2]; val.w = o[qs][dnt][3];
                *reinterpret_cast<float4*>(op + dnt * 16) = val;
            }
            if (lk == 0) {
                mlb[qs * 16 + lr] = m[qs];
                mlb[32 + qs * 16 + lr] = l[qs];
            }
        }
    } else {
#pragma unroll
        for (int qs = 0; qs < 2; qs++) {
            const float rl = 1.0f / l[qs];
            float* op = out + (size_t)(b_ * SE + q0 + qs * 16 + lr) * EB + h * DD + lk * 4;
#pragma unroll
            for (int dnt = 0; dnt < 4; dnt++) {
                float4 val;
                val.x = o[qs][dnt][0] * rl;
                val.y = o[qs][dnt][1] * rl;
                val.z = o[qs][dnt][2] * rl;
                val.w = o[qs][dnt][3] * rl;
                *reinterpret_cast<float4*>(op + dnt * 16) = val;
            }
        }
    }
}

// ---- combine: merge 2 split-S partials per (bh, q-chunk) ----
__global__ __launch_bounds__(64) void combine_kernel(
    const float* __restrict__ opart, const float* __restrict__ mlbuf,
    float* __restrict__ out) {
    const int g = blockIdx.x;            // bh*64 + qc
    const int bh = g >> 6, qc = g & 63;
    const int b_ = bh >> 3, h = bh & 7;
    const int lane = threadIdx.x;        // d
    const float CL = 11.54156031f;
    const float* o0 = opart + (size_t)g * 2 * 2048;
    const float* o1 = o0 + 2048;
    const float* ml0 = mlbuf + (size_t)g * 2 * 64;
    const float* ml1 = ml0 + 64;
#pragma unroll 4
    for (int q = 0; q < 32; q++) {
        const float m0 = ml0[q], l0 = ml0[32 + q];
        const float m1 = ml1[q], l1 = ml1[32 + q];
        const float M = fmaxf(m0, m1);
        const float e0 = EXP2((m0 - M) * CL);
        const float e1 = EXP2((m1 - M) * CL);
        const float rd = 1.0f / (e0 * l0 + e1 * l1);
        const float val = (e0 * o0[q * 64 + lane] + e1 * o1[q * 64 + lane]) * rd;
        out[(size_t)(b_ * SE + qc * 32 + q) * EB + h * DD + lane] = val;
    }
}

extern "C" void kernel_launch(void* const* d_in, const int* in_sizes, int n_in,
                              void* d_out, int out_size, void* d_ws, size_t ws_size,
                              hipStream_t stream) {
    const float* x  = (const float*)d_in[0];
    const float* wq = (const float*)d_in[1];
    const float* bq = (const float*)d_in[2];
    const float* wk = (const float*)d_in[3];
    const float* bk = (const float*)d_in[4];
    const float* wv = (const float*)d_in[5];
    const float* bv = (const float*)d_in[6];
    float* out = (float*)d_out;

    unsigned short* ws = (unsigned short*)d_ws;
    const int NX = 8192 * 512;
    const int NW = 3 * 512 * 512;
    const int NQ = BHN * SE * DD;
    unsigned short* xh  = ws;
    unsigned short* xl  = xh + NX;
    unsigned short* wth = xl + NX;
    unsigned short* wtl = wth + NW;
    unsigned short* qhp = wtl + NW;
    unsigned short* qlp = qhp + NQ;
    unsigned short* khp = qlp + NQ;
    unsigned short* klp = khp + NQ;
    unsigned short* vtp = klp + NQ;
    // split-S partials after the bf16 region
    const size_t bf16_elems = (size_t)2 * NX + 2 * NW + 5 * NQ;   // ushorts
    float* opart = (float*)(ws + bf16_elems);
    float* mlbuf = opart + (size_t)2048 * 2 * 2048;               // 33.5 MB
    const size_t need_bytes = bf16_elems * 2 + (size_t)2048 * 2 * 2048 * 4
                              + (size_t)2048 * 2 * 64 * 4;

    xsplit_kernel<<<NX / 4 / 256, 256, 0, stream>>>(x, xh, xl, NX / 4);
    wsplit_kernel<<<NW / 256, 256, 0, stream>>>(wq, wk, wv, wth, wtl);
    proj_kernel<1><<<dim3(64, 4, 2), 256, 0, stream>>>(xh, xl, wth, wtl, bq, bk, bv,
                                                       qhp, qlp, khp, klp, vtp);
    proj_kernel<0><<<dim3(64, 4), 256, 0, stream>>>(xh, xl, wth, wtl, bq, bk, bv,
                                                    qhp, qlp, khp, klp, vtp);
    if (ws_size >= need_bytes) {
        attn_kernel<1><<<dim3(32, 64, 2), 64, 0, stream>>>(qhp, qlp, khp, klp, vtp,
                                                           opart, mlbuf, out);
        combine_kernel<<<2048, 64, 0, stream>>>(opart, mlbuf, out);
    } else {
        attn_kernel<0><<<dim3(32, 64), 64, 0, stream>>>(qhp, qlp, khp, klp, vtp,
                                                        nullptr, nullptr, out);
    }
}